// Round 3
// baseline (165.650 us; speedup 1.0000x reference)
//
#include <hip/hip_runtime.h>

// Problem constants (match reference)
#define A_   5
#define C_   80
#define BB   16
#define HH   64
#define WW   64
#define NN   50
#define CH   (5 + C_)      // 85 channels per anchor
#define HW   (HH * WW)     // 4096
#define STRIDE_F 16.0f

// One block = 128 threads (2 waves) = one (b, a, 4 rows of h).
// Each thread handles 2 adjacent w-cells via float2 loads:
//   lane 0..31 -> row r, w = 2*(lane&31) + {0,1};  lane 32..63 -> row r+1.
// Per-wave: 5 float2 loads serve 128 cells; 250 LDS broadcast reads serve 128
// cells (both halved per-cell vs the 1-cell/thread version), and each thread
// carries two independent IoU argmax chains (2x ILP on the select chain).
__global__ __launch_bounds__(128)
void region_loss_kernel(const float* __restrict__ out4d,    // (B, A*85, 64, 64)
                        const float* __restrict__ target,   // (B, 50, 5): cls, cx, cy, w, h
                        const float* __restrict__ anchors,  // (5, 2)
                        float* __restrict__ loss)
{
    __shared__ float g_x1[NN], g_y1[NN], g_x2[NN], g_y2[NN], g_area[NN];
    __shared__ float g_cx[NN], g_cy[NN], g_w[NN], g_h[NN], g_cls[NN];
    __shared__ float wave_sum[2];

    const int bid = blockIdx.x;
    const int h4  = bid & 15;            // 16 groups of 4 rows
    const int a   = (bid >> 4) % A_;
    const int b   = bid / (A_ * 16);

    const int tid  = threadIdx.x;        // 0..127
    const int lane = tid & 63;
    const int w0   = (lane & 31) << 1;   // this thread's first w cell
    const int h    = (h4 << 2) + ((tid >> 6) << 1) + (lane >> 5);

    // Channel base for this (b, a, h, w0); channel stride = HW floats.
    const float* base = out4d + (size_t)(b * (A_ * CH) + a * CH) * HW + h * WW + w0;

    // Issue the 5 coalesced float2 channel loads first so HBM latency
    // overlaps the box staging (no dependence until after the barrier).
    const float2 v0 = *(const float2*)(base + 0 * HW);
    const float2 v1 = *(const float2*)(base + 1 * HW);
    const float2 v2 = *(const float2*)(base + 2 * HW);
    const float2 v3 = *(const float2*)(base + 3 * HW);
    const float2 vc = *(const float2*)(base + 4 * HW);

    // Stage GT boxes for this batch into LDS, pre-expanded to corners + area.
    if (tid < NN) {
        const float* t = target + ((size_t)b * NN + tid) * 5;
        float cls = t[0], cx = t[1], cy = t[2], gw = t[3], gh = t[4];
        g_cls[tid]  = cls;
        g_cx[tid]   = cx;  g_cy[tid] = cy;  g_w[tid] = gw;  g_h[tid] = gh;
        g_x1[tid]   = cx - gw * 0.5f;  g_y1[tid] = cy - gh * 0.5f;
        g_x2[tid]   = cx + gw * 0.5f;  g_y2[tid] = cy + gh * 0.5f;
        g_area[tid] = gw * gh + 1e-6f;   // +1e-6 of the union folded in
    }
    __syncthreads();

    const float aw = anchors[a * 2 + 0];   // block-uniform -> scalar load
    const float ah = anchors[a * 2 + 1];

    // Decode both predicted boxes.
    const float px0 = (1.0f / (1.0f + __expf(-v0.x)) + (float)(w0 + 0)) * STRIDE_F;
    const float py0 = (1.0f / (1.0f + __expf(-v1.x)) + (float)h) * STRIDE_F;
    const float pw0 = __expf(v2.x) * aw;
    const float ph0 = __expf(v3.x) * ah;
    const float ax1_0 = px0 - pw0 * 0.5f, ay1_0 = py0 - ph0 * 0.5f;
    const float ax2_0 = px0 + pw0 * 0.5f, ay2_0 = py0 + ph0 * 0.5f;
    const float pa0 = pw0 * ph0;

    const float px1 = (1.0f / (1.0f + __expf(-v0.y)) + (float)(w0 + 1)) * STRIDE_F;
    const float py1 = (1.0f / (1.0f + __expf(-v1.y)) + (float)h) * STRIDE_F;
    const float pw1 = __expf(v2.y) * aw;
    const float ph1 = __expf(v3.y) * ah;
    const float ax1_1 = px1 - pw1 * 0.5f, ay1_1 = py1 - ph1 * 0.5f;
    const float ax2_1 = px1 + pw1 * 0.5f, ay2_1 = py1 + ph1 * 0.5f;
    const float pa1 = pw1 * ph1;

    // Fused IoU argmax over 50 GT boxes for both cells; one set of LDS reads.
    // Cross-mult instead of divide; strict > keeps first index on ties (ref argmax).
    float bi0 = 0.0f, bu0 = 1.0f, bi1 = 0.0f, bu1 = 1.0f;
    int bn0 = 0, bn1 = 0;
    #pragma unroll 5
    for (int n = 0; n < NN; ++n) {
        const float gx1 = g_x1[n], gy1 = g_y1[n];
        const float gx2 = g_x2[n], gy2 = g_y2[n];
        const float ga  = g_area[n];

        float iw0 = fmaxf(fminf(gx2, ax2_0) - fmaxf(gx1, ax1_0), 0.0f);
        float ih0 = fmaxf(fminf(gy2, ay2_0) - fmaxf(gy1, ay1_0), 0.0f);
        float in0 = iw0 * ih0;
        float un0 = (ga + pa0) - in0;
        if (in0 * bu0 > bi0 * un0) { bi0 = in0; bu0 = un0; bn0 = n; }

        float iw1 = fmaxf(fminf(gx2, ax2_1) - fmaxf(gx1, ax1_1), 0.0f);
        float ih1 = fmaxf(fminf(gy2, ay2_1) - fmaxf(gy1, ay1_1), 0.0f);
        float in1 = iw1 * ih1;
        float un1 = (ga + pa1) - in1;
        if (in1 * bu1 > bi1 * un1) { bi1 = in1; bu1 = un1; bn1 = n; }
    }

    // Per-cell losses (fully unrolled j -> all selects are compile-time).
    float local = 0.0f;
    #pragma unroll
    for (int j = 0; j < 2; ++j) {
        const float bi = j ? bi1 : bi0;
        const float bu = j ? bu1 : bu0;
        const int   bn = j ? bn1 : bn0;
        const float X0 = j ? v0.y : v0.x;
        const float X1 = j ? v1.y : v1.x;
        const float X2 = j ? v2.y : v2.x;
        const float X3 = j ? v3.y : v3.x;
        const float CF = j ? vc.y : vc.x;

        if (bi > 0.6f * bu) {
            // Divergent branch: exec-masked loads fetch only masked lanes' lines;
            // s_cbranch_execz skips the body for clean waves.
            const float d0 = X0 - g_cx[bn];
            const float d1 = X1 - g_cy[bn];
            const float d2 = X2 - g_w[bn];
            const float d3 = X3 - g_h[bn];
            const float cd = 5.0f * CF - 5.0f;     // conf_mask=5, tconf=1

            const float* pc = base + j;
            // Class NLL: two-pass max-subtracted logsumexp.
            float m0 = -1e30f, m1 = -1e30f, m2 = -1e30f, m3 = -1e30f;
            #pragma unroll 5
            for (int c = 0; c < C_; c += 4) {
                m0 = fmaxf(m0, pc[(5 + c) * HW]);
                m1 = fmaxf(m1, pc[(6 + c) * HW]);
                m2 = fmaxf(m2, pc[(7 + c) * HW]);
                m3 = fmaxf(m3, pc[(8 + c) * HW]);
            }
            const float m = fmaxf(fmaxf(m0, m1), fmaxf(m2, m3));

            float s0 = 0.0f, s1 = 0.0f;
            #pragma unroll 10
            for (int c = 0; c < C_; c += 2) {
                s0 += __expf(pc[(5 + c) * HW] - m);
                s1 += __expf(pc[(6 + c) * HW] - m);
            }
            const int   tcls = (int)g_cls[bn];
            const float xt   = pc[(5 + tcls) * HW];
            local += d0*d0 + d1*d1 + d2*d2 + d3*d3 + cd*cd
                   + (m + __logf(s0 + s1) - xt);   // nll = lse - x[tcls]
        } else {
            local += CF * CF;                      // conf_mask=1, tconf=0
        }
    }

    // Wave (64-lane) shuffle reduction, then cross-wave via LDS, one atomic per block.
    for (int off = 32; off > 0; off >>= 1)
        local += __shfl_down(local, off);
    if (lane == 0) wave_sum[tid >> 6] = local;
    __syncthreads();
    if (tid == 0)
        atomicAdd(loss, wave_sum[0] + wave_sum[1]);
}

extern "C" void kernel_launch(void* const* d_in, const int* in_sizes, int n_in,
                              void* d_out, int out_size, void* d_ws, size_t ws_size,
                              hipStream_t stream) {
    const float* output  = (const float*)d_in[0];
    const float* target  = (const float*)d_in[1];
    const float* anchors = (const float*)d_in[2];
    float* loss = (float*)d_out;

    // Zero the scalar loss with a graph-capturable memset node.
    hipMemsetAsync(loss, 0, sizeof(float), stream);

    const int grid = BB * A_ * (HH / 4);   // 1280 blocks, 128 threads, 5 blocks/CU
    region_loss_kernel<<<grid, 128, 0, stream>>>(output, target, anchors, loss);
}

// Round 4
// 161.099 us; speedup vs baseline: 1.0283x; 1.0283x over previous
//
#include <hip/hip_runtime.h>

// Problem constants (match reference)
#define A_   5
#define C_   80
#define BB   16
#define HH   64
#define WW   64
#define NN   50
#define CH   (5 + C_)      // 85 channels per anchor
#define HW   (HH * WW)     // 4096
#define STRIDE_F 16.0f

// One block = one (b, a, 4 rows of h). 256 threads: lane (tid&63) = w, (tid>>6) = sub-row.
// 1280 blocks x 4 waves = 5120 waves = 20 waves/CU (best measured TLP config).
// IoU argmax runs as TWO interleaved 25-box chains per thread to halve the
// loop-carried select-dependency (the kernel is latency-bound, r3 evidence).
__global__ __launch_bounds__(256)
void region_loss_kernel(const float* __restrict__ out4d,    // (B, A*85, 64, 64)
                        const float* __restrict__ target,   // (B, 50, 5): cls, cx, cy, w, h
                        const float* __restrict__ anchors,  // (5, 2)
                        float* __restrict__ loss)
{
    __shared__ float g_x1[NN], g_y1[NN], g_x2[NN], g_y2[NN], g_area[NN];
    __shared__ float g_cx[NN], g_cy[NN], g_w[NN], g_h[NN], g_cls[NN];
    __shared__ float wave_sum[4];

    const int bid = blockIdx.x;
    const int h4  = bid & 15;            // 16 groups of 4 rows
    const int a   = (bid >> 4) % A_;
    const int b   = bid / (A_ * 16);

    const int tid = threadIdx.x;
    const int w   = tid & 63;
    const int h   = (h4 << 2) + (tid >> 6);

    // Channel base for this (b, a, h, w); channel stride = HW floats.
    const float* base = out4d + (size_t)(b * (A_ * CH) + a * CH) * HW + h * WW + w;

    // Issue the 5 coalesced channel loads FIRST so their HBM/L3 latency
    // overlaps the box staging below (no dependence until after the barrier).
    const float x0 = base[0 * HW];
    const float x1 = base[1 * HW];
    const float x2 = base[2 * HW];
    const float x3 = base[3 * HW];
    const float cf = base[4 * HW];

    // Stage GT boxes for this batch into LDS, pre-expanded to corners + area.
    if (tid < NN) {
        const float* t = target + ((size_t)b * NN + tid) * 5;
        float cls = t[0], cx = t[1], cy = t[2], gw = t[3], gh = t[4];
        g_cls[tid]  = cls;
        g_cx[tid]   = cx;  g_cy[tid] = cy;  g_w[tid] = gw;  g_h[tid] = gh;
        g_x1[tid]   = cx - gw * 0.5f;  g_y1[tid] = cy - gh * 0.5f;
        g_x2[tid]   = cx + gw * 0.5f;  g_y2[tid] = cy + gh * 0.5f;
        g_area[tid] = gw * gh + 1e-6f;   // +1e-6 of the union folded in
    }
    __syncthreads();

    const float aw = anchors[a * 2 + 0];   // block-uniform -> scalar load
    const float ah = anchors[a * 2 + 1];

    // Decode predicted box
    const float px = (1.0f / (1.0f + __expf(-x0)) + (float)w) * STRIDE_F;
    const float py = (1.0f / (1.0f + __expf(-x1)) + (float)h) * STRIDE_F;
    const float pw = __expf(x2) * aw;
    const float ph = __expf(x3) * ah;
    const float px1 = px - pw * 0.5f, py1 = py - ph * 0.5f;
    const float px2 = px + pw * 0.5f, py2 = py + ph * 0.5f;
    const float parea = pw * ph;

    // Argmax IoU over 50 GT boxes as two independent 25-iter chains (2x ILP
    // on the loop-carried select dep). Cross-mult instead of divide.
    // LDS broadcast reads (uniform n across lanes) are conflict-free.
    float iA = 0.0f, uA = 1.0f, iB = 0.0f, uB = 1.0f;
    int nA = 0, nB = NN / 2;
    #pragma unroll 5
    for (int n = 0; n < NN / 2; ++n) {
        // chain A: box n
        {
            float iw = fmaxf(fminf(g_x2[n], px2) - fmaxf(g_x1[n], px1), 0.0f);
            float ih = fmaxf(fminf(g_y2[n], py2) - fmaxf(g_y1[n], py1), 0.0f);
            float in_ = iw * ih;
            float un_ = (g_area[n] + parea) - in_;
            if (in_ * uA > iA * un_) { iA = in_; uA = un_; nA = n; }
        }
        // chain B: box n + 25
        {
            const int m = n + NN / 2;
            float iw = fmaxf(fminf(g_x2[m], px2) - fmaxf(g_x1[m], px1), 0.0f);
            float ih = fmaxf(fminf(g_y2[m], py2) - fmaxf(g_y1[m], py1), 0.0f);
            float in_ = iw * ih;
            float un_ = (g_area[m] + parea) - in_;
            if (in_ * uB > iB * un_) { iB = in_; uB = un_; nB = m; }
        }
    }
    // Merge: prefer chain A on ties (lower indices, matches reference argmax).
    float best_inter = iA, best_union = uA;
    int best_n = nA;
    if (iB * uA > iA * uB) { best_inter = iB; best_union = uB; best_n = nB; }

    const bool mask = best_inter > 0.6f * best_union;

    float local = cf * cf;                // conf_mask=1, tconf=0 (unmasked)
    if (mask) {
        // Divergent branch: exec-masked loads fetch only masked lanes' lines;
        // s_cbranch_execz skips the whole body for clean waves.
        const float d0 = x0 - g_cx[best_n];
        const float d1 = x1 - g_cy[best_n];
        const float d2 = x2 - g_w[best_n];
        const float d3 = x3 - g_h[best_n];
        const float cd = 5.0f * cf - 5.0f;   // conf_mask=5, tconf=1

        // Class NLL: two-pass max-subtracted logsumexp.
        // Pass 1: max with 4 independent accumulators.
        float m0 = -1e30f, m1 = -1e30f, m2 = -1e30f, m3 = -1e30f;
        #pragma unroll 5
        for (int c = 0; c < C_; c += 4) {
            m0 = fmaxf(m0, base[(5 + c) * HW]);
            m1 = fmaxf(m1, base[(6 + c) * HW]);
            m2 = fmaxf(m2, base[(7 + c) * HW]);
            m3 = fmaxf(m3, base[(8 + c) * HW]);
        }
        const float m = fmaxf(fmaxf(m0, m1), fmaxf(m2, m3));

        // Pass 2: sum of exp (reloads hit L1/L2), 2 independent accumulators.
        float s0 = 0.0f, s1 = 0.0f;
        #pragma unroll 10
        for (int c = 0; c < C_; c += 2) {
            s0 += __expf(base[(5 + c) * HW] - m);
            s1 += __expf(base[(6 + c) * HW] - m);
        }
        const int   tcls = (int)g_cls[best_n];
        const float xt   = base[(5 + tcls) * HW];   // direct gather
        local = d0*d0 + d1*d1 + d2*d2 + d3*d3 + cd*cd
              + (m + __logf(s0 + s1) - xt);         // nll = lse - x[tcls]
    }

    // Wave (64-lane) shuffle reduction, then cross-wave via LDS, one atomic per block.
    for (int off = 32; off > 0; off >>= 1)
        local += __shfl_down(local, off);
    if ((tid & 63) == 0) wave_sum[tid >> 6] = local;
    __syncthreads();
    if (tid == 0)
        atomicAdd(loss, wave_sum[0] + wave_sum[1] + wave_sum[2] + wave_sum[3]);
}

extern "C" void kernel_launch(void* const* d_in, const int* in_sizes, int n_in,
                              void* d_out, int out_size, void* d_ws, size_t ws_size,
                              hipStream_t stream) {
    const float* output  = (const float*)d_in[0];
    const float* target  = (const float*)d_in[1];
    const float* anchors = (const float*)d_in[2];
    float* loss = (float*)d_out;

    // Zero the scalar loss with a graph-capturable memset node.
    hipMemsetAsync(loss, 0, sizeof(float), stream);

    const int grid = BB * A_ * (HH / 4);   // 1280 blocks, 256 threads, 20 waves/CU
    region_loss_kernel<<<grid, 256, 0, stream>>>(output, target, anchors, loss);
}